// Round 1
// baseline (1403.530 us; speedup 1.0000x reference)
//
#include <hip/hip_runtime.h>

#define EPS_ODIN 0.0014f

constexpr int Bb = 1024;   // batch
constexpr int Cc = 100;    // classes
constexpr int Dd = 512;    // feature dim
constexpr int INn = 3072;  // input dim (3*32*32)

// Generic fp32 tiled GEMM: C[M,N] = A[M,K] @ B  (TRANSB=false: B is [K,N]; true: B is [N,K])
// Epilogues: 0 = none; 1 = relu(acc + aux1[n]) (bias+relu);
//            2 = clip(aux1[m*N+n] + esc*acc, 0, 1)  (FGSM step, aux1 = x);
//            3 = 2*acc - aux1[m] - aux2[n]          (final scores, aux1=s, aux2=q)
template<bool TRANSB, int EPI>
__global__ __launch_bounds__(256) void gemm_f32(
    const float* __restrict__ A, const float* __restrict__ Bm,
    float* __restrict__ Cm, int M, int N, int K,
    const float* __restrict__ aux1, const float* __restrict__ aux2, float esc)
{
    __shared__ float As[32][64];
    __shared__ float Bs[32][64];
    const int tid = threadIdx.x;
    const int m0 = blockIdx.y * 64;
    const int n0 = blockIdx.x * 64;
    const int tx = tid & 15, ty = tid >> 4;
    const int tm = ty * 4, tn = tx * 4;
    float acc[4][4] = {};

    for (int k0 = 0; k0 < K; k0 += 32) {
        // A tile: 64 rows x 32 k, coalesced on k
        #pragma unroll
        for (int i = 0; i < 8; ++i) {
            int idx = i * 256 + tid;
            int k = idx & 31, m = idx >> 5;
            int gm = m0 + m;
            As[k][m] = (gm < M) ? A[(long)gm * K + k0 + k] : 0.f;
        }
        if (!TRANSB) {
            #pragma unroll
            for (int i = 0; i < 8; ++i) {
                int idx = i * 256 + tid;
                int n = idx & 63, k = idx >> 6;
                int gn = n0 + n;
                Bs[k][n] = (gn < N) ? Bm[(long)(k0 + k) * N + gn] : 0.f;
            }
        } else {
            #pragma unroll
            for (int i = 0; i < 8; ++i) {
                int idx = i * 256 + tid;
                int k = idx & 31, n = idx >> 5;
                int gn = n0 + n;
                Bs[k][n] = (gn < N) ? Bm[(long)gn * K + k0 + k] : 0.f;
            }
        }
        __syncthreads();
        #pragma unroll
        for (int k = 0; k < 32; ++k) {
            float a[4], bf[4];
            #pragma unroll
            for (int i = 0; i < 4; ++i) a[i] = As[k][tm + i];
            #pragma unroll
            for (int j = 0; j < 4; ++j) bf[j] = Bs[k][tn + j];
            #pragma unroll
            for (int i = 0; i < 4; ++i)
                #pragma unroll
                for (int j = 0; j < 4; ++j)
                    acc[i][j] = fmaf(a[i], bf[j], acc[i][j]);
        }
        __syncthreads();
    }

    #pragma unroll
    for (int i = 0; i < 4; ++i) {
        int gm = m0 + tm + i;
        if (gm >= M) continue;
        #pragma unroll
        for (int j = 0; j < 4; ++j) {
            int gn = n0 + tn + j;
            if (gn >= N) continue;
            long cidx = (long)gm * N + gn;
            float v = acc[i][j];
            if (EPI == 1) v = fmaxf(v + aux1[gn], 0.f);
            else if (EPI == 2) { v = aux1[cidx] + esc * v; v = fminf(fmaxf(v, 0.f), 1.f); }
            else if (EPI == 3) v = 2.f * v - aux1[gm] - aux2[gn];
            Cm[cidx] = v;
        }
    }
}

// q[c] = mu[c,:] . im[c,:]
__global__ void rowdot_kernel(const float* __restrict__ a, const float* __restrict__ bp,
                              float* __restrict__ outv, int ncols)
{
    int r = blockIdx.x;
    int lane = threadIdx.x;
    float sum = 0.f;
    for (int d = lane; d < ncols; d += 64)
        sum += a[(long)r * ncols + d] * bp[(long)r * ncols + d];
    #pragma unroll
    for (int off = 32; off; off >>= 1) sum += __shfl_down(sum, off);
    if (lane == 0) outv[r] = sum;
}

// cstar[b] = argmax_c (2*t[b,c] - q[c])
__global__ void argmax_kernel(const float* __restrict__ t, const float* __restrict__ q,
                              int* __restrict__ cstar)
{
    int b = blockIdx.x * blockDim.x + threadIdx.x;
    if (b >= Bb) return;
    float best = -INFINITY; int bi = 0;
    for (int c = 0; c < Cc; ++c) {
        float v = 2.f * t[b * Cc + c] - q[c];
        if (v > best) { best = v; bi = c; }
    }
    cstar[b] = bi;
}

// dz[b,d] = (feat>0) ? -2*(h[b,d] - im[cstar[b], d]) : 0
__global__ void dz_kernel(const float* __restrict__ feat, const float* __restrict__ h,
                          const float* __restrict__ im, const int* __restrict__ cstar,
                          float* __restrict__ dz)
{
    int idx = blockIdx.x * blockDim.x + threadIdx.x;
    if (idx >= Bb * Dd) return;
    int b = idx >> 9;          // /512
    int d = idx & 511;         // %512
    float f = feat[idx];
    dz[idx] = (f > 0.f) ? -2.f * (h[idx] - im[cstar[b] * Dd + d]) : 0.f;
}

extern "C" void kernel_launch(void* const* d_in, const int* in_sizes, int n_in,
                              void* d_out, int out_size, void* d_ws, size_t ws_size,
                              hipStream_t stream)
{
    const float* x      = (const float*)d_in[0];  // [1024,3,32,32]
    const float* W      = (const float*)d_in[1];  // [3072,512]
    const float* bias   = (const float*)d_in[2];  // [512]
    const float* mu     = (const float*)d_in[3];  // [100,512]
    const float* invsig = (const float*)d_in[4];  // [512,512]
    float* out = (float*)d_out;                   // [1024,100]

    char* wp = (char*)d_ws;
    auto alloc = [&](size_t bytes) { char* p = wp; wp += (bytes + 255) & ~size_t(255); return p; };
    float* feat = (float*)alloc((size_t)Bb * Dd * 4);
    float* h    = (float*)alloc((size_t)Bb * Dd * 4);
    float* im   = (float*)alloc((size_t)Cc * Dd * 4);
    float* q    = (float*)alloc(512);
    float* s    = (float*)alloc((size_t)Bb * 4);
    int*   cst  = (int*)  alloc((size_t)Bb * 4);
    float* t    = (float*)alloc((size_t)Bb * Cc * 4);
    float* dz   = (float*)alloc((size_t)Bb * Dd * 4);
    float* xadv = (float*)alloc((size_t)Bb * INn * 4);

    dim3 blk(256);
    auto grd = [](int M, int N) { return dim3((N + 63) / 64, (M + 63) / 64); };

    // Precompute: im = mu @ invsig (invsig symmetric), q[c] = mu_c . im_c
    gemm_f32<false,0><<<grd(Cc, Dd), blk, 0, stream>>>(mu, invsig, im, Cc, Dd, Dd, nullptr, nullptr, 0.f);
    rowdot_kernel<<<Cc, 64, 0, stream>>>(mu, im, q, Dd);

    // Pass A: feat = relu(x@W + b); h = feat@invsig; t = h@mu^T; argmax
    gemm_f32<false,1><<<grd(Bb, Dd), blk, 0, stream>>>(x, W, feat, Bb, Dd, INn, bias, nullptr, 0.f);
    gemm_f32<false,0><<<grd(Bb, Dd), blk, 0, stream>>>(feat, invsig, h, Bb, Dd, Dd, nullptr, nullptr, 0.f);
    gemm_f32<true, 0><<<grd(Bb, Cc), blk, 0, stream>>>(h, mu, t, Bb, Cc, Dd, nullptr, nullptr, 0.f);
    argmax_kernel<<<Bb / 256, 256, 0, stream>>>(t, q, cst);

    // Backward: dz; g = dz @ W^T, fused FGSM step -> xadv
    dz_kernel<<<(Bb * Dd) / 256, 256, 0, stream>>>(feat, h, im, cst, dz);
    gemm_f32<true, 2><<<grd(Bb, INn), blk, 0, stream>>>(dz, W, xadv, Bb, INn, Dd, x, nullptr, EPS_ODIN);

    // Pass B: feat2 = relu(xadv@W + b); h2 = feat2@invsig; s2; out = 2*(h2@mu^T) - s2 - q
    gemm_f32<false,1><<<grd(Bb, Dd), blk, 0, stream>>>(xadv, W, feat, Bb, Dd, INn, bias, nullptr, 0.f);
    gemm_f32<false,0><<<grd(Bb, Dd), blk, 0, stream>>>(feat, invsig, h, Bb, Dd, Dd, nullptr, nullptr, 0.f);
    rowdot_kernel<<<Bb, 64, 0, stream>>>(feat, h, s, Dd);
    gemm_f32<true, 3><<<grd(Bb, Cc), blk, 0, stream>>>(h, mu, out, Bb, Cc, Dd, s, q, 0.f);
}

// Round 2
// 358.384 us; speedup vs baseline: 3.9163x; 3.9163x over previous
//
#include <hip/hip_runtime.h>
#include <hip/hip_bf16.h>

#define EPS_ODIN 0.0014f

constexpr int Bb = 1024;   // batch
constexpr int Cc = 100;    // classes
constexpr int Dd = 512;    // feature dim
constexpr int INn = 3072;  // input dim (3*32*32)

using s16x8 = __attribute__((ext_vector_type(8))) short;
using f32x4 = __attribute__((ext_vector_type(4))) float;

__device__ __forceinline__ short f2bf(float f) {
    __hip_bfloat16 h = __float2bfloat16(f);
    return *reinterpret_cast<short*>(&h);
}
__device__ __forceinline__ float bf2f(short s) {
    __hip_bfloat16 h;
    *reinterpret_cast<short*>(&h) = s;
    return __bfloat162float(h);
}

// C[M,N] = A[M,K] @ B^T where B is given as [N,K] row-major (both operands K-major).
// bf16x3 split precision: acc = Ahi*Bhi + Ahi*Blo + Alo*Bhi  (~fp32 accuracy).
// Epilogues: 0 none; 1 relu(acc+aux1[n]); 2 clip(aux1[m*N+n]+esc*acc,0,1); 3 2*acc-aux1[m]-aux2[n]
template<int EPI>
__global__ __launch_bounds__(256) void gemm_bf16x3(
    const float* __restrict__ A, const float* __restrict__ Bm,
    float* __restrict__ Cm, int M, int N, int K,
    const float* __restrict__ aux1, const float* __restrict__ aux2, float esc)
{
    // LDS tiles: [hi/lo][64 rows][BK=32 k, stride 40 -> 80B row pitch, conflict-free b128]
    __shared__ short As[2][64 * 40];
    __shared__ short Bs[2][64 * 40];

    const int tid = threadIdx.x;
    const int m0 = blockIdx.y * 64, n0 = blockIdx.x * 64;
    const int lane = tid & 63, w = tid >> 6;
    const int wm = (w >> 1) * 32, wn = (w & 1) * 32;
    const int lrow = lane & 15, kseg = lane >> 4;   // fragment row, k-segment (8 k each)

    const int sr = tid >> 2;            // staging row 0..63
    const int sk = (tid & 3) * 8;       // staging k offset 0,8,16,24

    f32x4 acc[2][2];
    #pragma unroll
    for (int i = 0; i < 2; ++i)
        #pragma unroll
        for (int j = 0; j < 2; ++j)
            acc[i][j] = f32x4{0.f, 0.f, 0.f, 0.f};

    for (int k0 = 0; k0 < K; k0 += 32) {
        // ---- stage A tile (rows of A) ----
        {
            float v[8];
            int gr = m0 + sr;
            if (gr < M) {
                const float* p = A + (long)gr * K + k0 + sk;
                *(f32x4*)(v)     = *(const f32x4*)(p);
                *(f32x4*)(v + 4) = *(const f32x4*)(p + 4);
            } else {
                #pragma unroll
                for (int j = 0; j < 8; ++j) v[j] = 0.f;
            }
            short hi[8], lo[8];
            #pragma unroll
            for (int j = 0; j < 8; ++j) {
                hi[j] = f2bf(v[j]);
                lo[j] = f2bf(v[j] - bf2f(hi[j]));
            }
            *(s16x8*)&As[0][sr * 40 + sk] = *(s16x8*)hi;
            *(s16x8*)&As[1][sr * 40 + sk] = *(s16x8*)lo;
        }
        // ---- stage B tile (rows of B = columns of B^T) ----
        {
            float v[8];
            int gr = n0 + sr;
            if (gr < N) {
                const float* p = Bm + (long)gr * K + k0 + sk;
                *(f32x4*)(v)     = *(const f32x4*)(p);
                *(f32x4*)(v + 4) = *(const f32x4*)(p + 4);
            } else {
                #pragma unroll
                for (int j = 0; j < 8; ++j) v[j] = 0.f;
            }
            short hi[8], lo[8];
            #pragma unroll
            for (int j = 0; j < 8; ++j) {
                hi[j] = f2bf(v[j]);
                lo[j] = f2bf(v[j] - bf2f(hi[j]));
            }
            *(s16x8*)&Bs[0][sr * 40 + sk] = *(s16x8*)hi;
            *(s16x8*)&Bs[1][sr * 40 + sk] = *(s16x8*)lo;
        }
        __syncthreads();

        s16x8 ah[2], al[2], bh[2], bl[2];
        #pragma unroll
        for (int i = 0; i < 2; ++i) {
            ah[i] = *(const s16x8*)&As[0][(wm + i * 16 + lrow) * 40 + kseg * 8];
            al[i] = *(const s16x8*)&As[1][(wm + i * 16 + lrow) * 40 + kseg * 8];
            bh[i] = *(const s16x8*)&Bs[0][(wn + i * 16 + lrow) * 40 + kseg * 8];
            bl[i] = *(const s16x8*)&Bs[1][(wn + i * 16 + lrow) * 40 + kseg * 8];
        }
        #pragma unroll
        for (int i = 0; i < 2; ++i)
            #pragma unroll
            for (int j = 0; j < 2; ++j) {
                acc[i][j] = __builtin_amdgcn_mfma_f32_16x16x32_bf16(ah[i], bh[j], acc[i][j], 0, 0, 0);
                acc[i][j] = __builtin_amdgcn_mfma_f32_16x16x32_bf16(ah[i], bl[j], acc[i][j], 0, 0, 0);
                acc[i][j] = __builtin_amdgcn_mfma_f32_16x16x32_bf16(al[i], bh[j], acc[i][j], 0, 0, 0);
            }
        __syncthreads();
    }

    // Epilogue. C/D layout: col = lane&15, row = (lane>>4)*4 + reg  [verified m89/m91]
    const int crow = (lane >> 4) * 4;
    const int ccol = lane & 15;
    #pragma unroll
    for (int i = 0; i < 2; ++i)
        #pragma unroll
        for (int j = 0; j < 2; ++j)
            #pragma unroll
            for (int r = 0; r < 4; ++r) {
                int gm = m0 + wm + i * 16 + crow + r;
                int gn = n0 + wn + j * 16 + ccol;
                if (gm < M && gn < N) {
                    long cidx = (long)gm * N + gn;
                    float v = acc[i][j][r];
                    if (EPI == 1) v = fmaxf(v + aux1[gn], 0.f);
                    else if (EPI == 2) { v = aux1[cidx] + esc * v; v = fminf(fmaxf(v, 0.f), 1.f); }
                    else if (EPI == 3) v = 2.f * v - aux1[gm] - aux2[gn];
                    Cm[cidx] = v;
                }
            }
}

// out[C,R] = in[R,C]^T  (fp32 tiled transpose)
__global__ __launch_bounds__(256) void transpose_f32(const float* __restrict__ in,
                                                     float* __restrict__ outp, int R, int C)
{
    __shared__ float t[32][33];
    int c0 = blockIdx.x * 32, r0 = blockIdx.y * 32;
    int tx = threadIdx.x & 31, ty = threadIdx.x >> 5;  // 32 x 8
    #pragma unroll
    for (int i = 0; i < 4; ++i) {
        int r = r0 + ty + i * 8;
        if (r < R && c0 + tx < C) t[ty + i * 8][tx] = in[(long)r * C + c0 + tx];
    }
    __syncthreads();
    #pragma unroll
    for (int i = 0; i < 4; ++i) {
        int c = c0 + ty + i * 8;
        if (c < C && r0 + tx < R) outp[(long)c * R + r0 + tx] = t[tx][ty + i * 8];
    }
}

// q[r] = a[r,:] . bp[r,:]
__global__ void rowdot_kernel(const float* __restrict__ a, const float* __restrict__ bp,
                              float* __restrict__ outv, int ncols)
{
    int r = blockIdx.x;
    int lane = threadIdx.x;
    float sum = 0.f;
    for (int d = lane; d < ncols; d += 64)
        sum += a[(long)r * ncols + d] * bp[(long)r * ncols + d];
    #pragma unroll
    for (int off = 32; off; off >>= 1) sum += __shfl_down(sum, off);
    if (lane == 0) outv[r] = sum;
}

// cstar[b] = argmax_c (2*t[b,c] - q[c])
__global__ void argmax_kernel(const float* __restrict__ t, const float* __restrict__ q,
                              int* __restrict__ cstar)
{
    int b = blockIdx.x * blockDim.x + threadIdx.x;
    if (b >= Bb) return;
    float best = -INFINITY; int bi = 0;
    for (int c = 0; c < Cc; ++c) {
        float v = 2.f * t[b * Cc + c] - q[c];
        if (v > best) { best = v; bi = c; }
    }
    cstar[b] = bi;
}

// dz[b,d] = (feat>0) ? -2*(h[b,d] - im[cstar[b], d]) : 0
__global__ void dz_kernel(const float* __restrict__ feat, const float* __restrict__ h,
                          const float* __restrict__ im, const int* __restrict__ cstar,
                          float* __restrict__ dz)
{
    int idx = blockIdx.x * blockDim.x + threadIdx.x;
    if (idx >= Bb * Dd) return;
    int b = idx >> 9;
    int d = idx & 511;
    float f = feat[idx];
    dz[idx] = (f > 0.f) ? -2.f * (h[idx] - im[cstar[b] * Dd + d]) : 0.f;
}

extern "C" void kernel_launch(void* const* d_in, const int* in_sizes, int n_in,
                              void* d_out, int out_size, void* d_ws, size_t ws_size,
                              hipStream_t stream)
{
    const float* x      = (const float*)d_in[0];  // [1024,3072]
    const float* W      = (const float*)d_in[1];  // [3072,512]
    const float* bias   = (const float*)d_in[2];  // [512]
    const float* mu     = (const float*)d_in[3];  // [100,512]
    const float* invsig = (const float*)d_in[4];  // [512,512] symmetric
    float* out = (float*)d_out;                   // [1024,100]

    char* wp = (char*)d_ws;
    auto alloc = [&](size_t bytes) { char* p = wp; wp += (bytes + 255) & ~size_t(255); return p; };
    float* Wt   = (float*)alloc((size_t)Dd * INn * 4);  // W^T [512,3072]
    float* feat = (float*)alloc((size_t)Bb * Dd * 4);
    float* h    = (float*)alloc((size_t)Bb * Dd * 4);
    float* im   = (float*)alloc((size_t)Cc * Dd * 4);
    float* q    = (float*)alloc(512);
    float* s    = (float*)alloc((size_t)Bb * 4);
    int*   cst  = (int*)  alloc((size_t)Bb * 4);
    float* t    = (float*)alloc((size_t)Bb * Cc * 4);
    float* dz   = (float*)alloc((size_t)Bb * Dd * 4);
    float* xadv = (float*)alloc((size_t)Bb * INn * 4);

    dim3 blk(256);
    auto grd = [](int M, int N) { return dim3((N + 63) / 64, (M + 63) / 64); };

    // W^T for the x@W GEMMs (B operand must be [N,K])
    transpose_f32<<<dim3((Dd + 31) / 32, (INn + 31) / 32), blk, 0, stream>>>(W, Wt, INn, Dd);

    // Precompute: im = mu @ invsig (symmetric), q[c] = mu_c . im_c
    gemm_bf16x3<0><<<grd(Cc, Dd), blk, 0, stream>>>(mu, invsig, im, Cc, Dd, Dd, nullptr, nullptr, 0.f);
    rowdot_kernel<<<Cc, 64, 0, stream>>>(mu, im, q, Dd);

    // Pass A: feat = relu(x@W + b); h = feat@invsig; t = h@mu^T; argmax
    gemm_bf16x3<1><<<grd(Bb, Dd), blk, 0, stream>>>(x, Wt, feat, Bb, Dd, INn, bias, nullptr, 0.f);
    gemm_bf16x3<0><<<grd(Bb, Dd), blk, 0, stream>>>(feat, invsig, h, Bb, Dd, Dd, nullptr, nullptr, 0.f);
    gemm_bf16x3<0><<<grd(Bb, Cc), blk, 0, stream>>>(h, mu, t, Bb, Cc, Dd, nullptr, nullptr, 0.f);
    argmax_kernel<<<Bb / 256, 256, 0, stream>>>(t, q, cst);

    // Backward: dz; g = dz @ W^T (B = W as [N=3072,K=512]); fused FGSM -> xadv
    dz_kernel<<<(Bb * Dd) / 256, 256, 0, stream>>>(feat, h, im, cst, dz);
    gemm_bf16x3<2><<<grd(Bb, INn), blk, 0, stream>>>(dz, W, xadv, Bb, INn, Dd, x, nullptr, EPS_ODIN);

    // Pass B: feat2 = relu(xadv@W + b); h2; s2; out = 2*(h2@mu^T) - s2 - q
    gemm_bf16x3<1><<<grd(Bb, Dd), blk, 0, stream>>>(xadv, Wt, feat, Bb, Dd, INn, bias, nullptr, 0.f);
    gemm_bf16x3<0><<<grd(Bb, Dd), blk, 0, stream>>>(feat, invsig, h, Bb, Dd, Dd, nullptr, nullptr, 0.f);
    rowdot_kernel<<<Bb, 64, 0, stream>>>(feat, h, s, Dd);
    gemm_bf16x3<3><<<grd(Bb, Cc), blk, 0, stream>>>(h, mu, out, Bb, Cc, Dd, s, q, 0.f);
}

// Round 3
// 189.961 us; speedup vs baseline: 7.3885x; 1.8866x over previous
//
#include <hip/hip_runtime.h>
#include <hip/hip_bf16.h>

#define EPS_ODIN 0.0014f

constexpr int Bb = 1024;   // batch
constexpr int Cc = 100;    // classes
constexpr int Dd = 512;    // feature dim
constexpr int INn = 3072;  // input dim

using s16x8 = __attribute__((ext_vector_type(8))) short;
using s16x4 = __attribute__((ext_vector_type(4))) short;
using f32x4 = __attribute__((ext_vector_type(4))) float;

__device__ __forceinline__ short f2bf(float f) {
    __hip_bfloat16 h = __float2bfloat16(f);
    return *reinterpret_cast<short*>(&h);
}
__device__ __forceinline__ float bf2f(short s) {
    __hip_bfloat16 h;
    *reinterpret_cast<short*>(&h) = s;
    return __bfloat162float(h);
}

constexpr int PITCH = 68;  // shorts; 136B row pitch -> uniform bank spread for b128 ops

// C[M,N] = A[M,K] @ B^T, A/B pre-split bf16 hi/lo, both [rows, K] row-major.
// bf16x3: acc = Ah*Bh + Ah*Bl + Al*Bh. Block tile 128x64, 4 waves of 32x64, BK=64.
// EPI: 0 plain fp32; 2 clip(aux1+esc*acc,0,1)->hl only; 3 2*acc-aux1[m]-aux2[n]; 4 fp32+hl.
// SPLIT: write raw partials to Cm + z*M*N (epilogue done by reducer).
template<int EPI, bool SPLIT>
__global__ __launch_bounds__(256, 2) void gemm_hl(
    const short* __restrict__ Ah, const short* __restrict__ Al,
    const short* __restrict__ Bh, const short* __restrict__ Bl,
    float* __restrict__ Cm, int M, int N, int K, int kcount,
    const float* __restrict__ aux1, const float* __restrict__ aux2, float esc,
    short* __restrict__ oh, short* __restrict__ ol)
{
    __shared__ short As[2][128 * PITCH];
    __shared__ short Bs[2][64 * PITCH];
    const int tid = threadIdx.x;
    const int m0 = blockIdx.y * 128, n0 = blockIdx.x * 64;
    const long kbeg = (long)blockIdx.z * kcount;
    const int lane = tid & 63, w = tid >> 6;
    const int wm = w * 32;
    const int lrow = lane & 15, kseg = lane >> 4;
    const int srow = tid >> 3, skc = tid & 7;

    f32x4 acc[2][4];
    #pragma unroll
    for (int i = 0; i < 2; ++i)
        #pragma unroll
        for (int j = 0; j < 4; ++j)
            acc[i][j] = f32x4{0.f, 0.f, 0.f, 0.f};

    const s16x8 ZV = {0, 0, 0, 0, 0, 0, 0, 0};
    const int nkt = kcount >> 6;
    s16x8 rA[4][2], rB[2][2];

    auto ldA = [&](int kt) {
        #pragma unroll
        for (int i = 0; i < 4; ++i) {
            int gr = m0 + srow + i * 32;
            long off = (long)gr * K + kbeg + kt * 64 + skc * 8;
            if (gr < M) { rA[i][0] = *(const s16x8*)(Ah + off); rA[i][1] = *(const s16x8*)(Al + off); }
            else        { rA[i][0] = ZV; rA[i][1] = ZV; }
        }
    };
    auto ldB = [&](int kt) {
        #pragma unroll
        for (int i = 0; i < 2; ++i) {
            int gn = n0 + srow + i * 32;
            long off = (long)gn * K + kbeg + kt * 64 + skc * 8;
            if (gn < N) { rB[i][0] = *(const s16x8*)(Bh + off); rB[i][1] = *(const s16x8*)(Bl + off); }
            else        { rB[i][0] = ZV; rB[i][1] = ZV; }
        }
    };

    ldA(0); ldB(0);
    for (int kt = 0; kt < nkt; ++kt) {
        #pragma unroll
        for (int i = 0; i < 4; ++i) {
            int r = srow + i * 32;
            *(s16x8*)&As[0][r * PITCH + skc * 8] = rA[i][0];
            *(s16x8*)&As[1][r * PITCH + skc * 8] = rA[i][1];
        }
        #pragma unroll
        for (int i = 0; i < 2; ++i) {
            int r = srow + i * 32;
            *(s16x8*)&Bs[0][r * PITCH + skc * 8] = rB[i][0];
            *(s16x8*)&Bs[1][r * PITCH + skc * 8] = rB[i][1];
        }
        __syncthreads();
        if (kt + 1 < nkt) { ldA(kt + 1); ldB(kt + 1); }
        #pragma unroll
        for (int kk = 0; kk < 2; ++kk) {
            s16x8 ah[2], al[2], bh[4], bl[4];
            #pragma unroll
            for (int i = 0; i < 2; ++i) {
                int rr = (wm + i * 16 + lrow) * PITCH + kk * 32 + kseg * 8;
                ah[i] = *(const s16x8*)&As[0][rr];
                al[i] = *(const s16x8*)&As[1][rr];
            }
            #pragma unroll
            for (int j = 0; j < 4; ++j) {
                int rr = (j * 16 + lrow) * PITCH + kk * 32 + kseg * 8;
                bh[j] = *(const s16x8*)&Bs[0][rr];
                bl[j] = *(const s16x8*)&Bs[1][rr];
            }
            #pragma unroll
            for (int i = 0; i < 2; ++i)
                #pragma unroll
                for (int j = 0; j < 4; ++j) {
                    acc[i][j] = __builtin_amdgcn_mfma_f32_16x16x32_bf16(ah[i], bh[j], acc[i][j], 0, 0, 0);
                    acc[i][j] = __builtin_amdgcn_mfma_f32_16x16x32_bf16(ah[i], bl[j], acc[i][j], 0, 0, 0);
                    acc[i][j] = __builtin_amdgcn_mfma_f32_16x16x32_bf16(al[i], bh[j], acc[i][j], 0, 0, 0);
                }
        }
        __syncthreads();
    }

    const int crow = (lane >> 4) * 4, ccol = lane & 15;
    #pragma unroll
    for (int i = 0; i < 2; ++i)
        #pragma unroll
        for (int j = 0; j < 4; ++j)
            #pragma unroll
            for (int r = 0; r < 4; ++r) {
                int gm = m0 + wm + i * 16 + crow + r;
                int gn = n0 + j * 16 + ccol;
                if (gm < M && gn < N) {
                    long cidx = (long)gm * N + gn;
                    float v = acc[i][j][r];
                    if (SPLIT) {
                        (Cm + (long)blockIdx.z * M * N)[cidx] = v;
                    } else if (EPI == 2) {
                        v = aux1[cidx] + esc * v;
                        v = fminf(fmaxf(v, 0.f), 1.f);
                        short hi = f2bf(v);
                        oh[cidx] = hi; ol[cidx] = f2bf(v - bf2f(hi));
                    } else if (EPI == 3) {
                        Cm[cidx] = 2.f * v - aux1[gm] - aux2[gn];
                    } else if (EPI == 4) {
                        Cm[cidx] = v;
                        short hi = f2bf(v);
                        oh[cidx] = hi; ol[cidx] = f2bf(v - bf2f(hi));
                    } else {
                        Cm[cidx] = v;
                    }
                }
            }
}

// Sum 4 split-K partials of x@W, add bias, ReLU, emit fp32 + bf16 hi/lo.
__global__ void reduce_relu(const float* __restrict__ part, const float* __restrict__ bias,
                            float* __restrict__ f32o, short* __restrict__ oh, short* __restrict__ ol)
{
    const long MN = (long)Bb * Dd;
    long idx = ((long)blockIdx.x * 256 + threadIdx.x) * 4;
    f32x4 v = *(const f32x4*)(part + idx);
    #pragma unroll
    for (int s2 = 1; s2 < 4; ++s2) {
        f32x4 u = *(const f32x4*)(part + s2 * MN + idx);
        v = v + u;
    }
    int gn = (int)(idx & (Dd - 1));
    f32x4 bb = *(const f32x4*)(bias + gn);
    f32x4 o; s16x4 h4, l4;
    #pragma unroll
    for (int j = 0; j < 4; ++j) {
        float t = fmaxf(v[j] + bb[j], 0.f);
        o[j] = t;
        short hi = f2bf(t);
        h4[j] = hi; l4[j] = f2bf(t - bf2f(hi));
    }
    *(f32x4*)(f32o + idx) = o;
    *(s16x4*)(oh + idx) = h4;
    *(s16x4*)(ol + idx) = l4;
}

// fp32 -> bf16 hi/lo split, 4 elems/thread
__global__ void split_hl_k(const float* __restrict__ in, short* __restrict__ oh,
                           short* __restrict__ ol, int n4)
{
    int i = blockIdx.x * 256 + threadIdx.x;
    if (i >= n4) return;
    long idx = (long)i * 4;
    f32x4 v = *(const f32x4*)(in + idx);
    s16x4 h4, l4;
    #pragma unroll
    for (int j = 0; j < 4; ++j) {
        short hi = f2bf(v[j]);
        h4[j] = hi; l4[j] = f2bf(v[j] - bf2f(hi));
    }
    *(s16x4*)(oh + idx) = h4;
    *(s16x4*)(ol + idx) = l4;
}

// W [R,C] -> Wt hi/lo [C,R]
__global__ __launch_bounds__(256) void transpose_split(const float* __restrict__ in,
                                                       short* __restrict__ oh, short* __restrict__ ol,
                                                       int R, int C)
{
    __shared__ float t[32][33];
    int c0 = blockIdx.x * 32, r0 = blockIdx.y * 32;
    int tx = threadIdx.x & 31, ty = threadIdx.x >> 5;
    #pragma unroll
    for (int i = 0; i < 4; ++i)
        t[ty + i * 8][tx] = in[(long)(r0 + ty + i * 8) * C + c0 + tx];
    __syncthreads();
    #pragma unroll
    for (int i = 0; i < 4; ++i) {
        int c = c0 + ty + i * 8;
        float v = t[tx][ty + i * 8];
        short hi = f2bf(v);
        oh[(long)c * R + r0 + tx] = hi;
        ol[(long)c * R + r0 + tx] = f2bf(v - bf2f(hi));
    }
}

__global__ void rowdot_kernel(const float* __restrict__ a, const float* __restrict__ bp,
                              float* __restrict__ outv, int ncols)
{
    int r = blockIdx.x;
    int lane = threadIdx.x;
    float sum = 0.f;
    for (int d = lane; d < ncols; d += 64)
        sum += a[(long)r * ncols + d] * bp[(long)r * ncols + d];
    #pragma unroll
    for (int off = 32; off; off >>= 1) sum += __shfl_down(sum, off);
    if (lane == 0) outv[r] = sum;
}

__global__ void argmax_kernel(const float* __restrict__ t, const float* __restrict__ q,
                              int* __restrict__ cstar)
{
    int b = blockIdx.x * blockDim.x + threadIdx.x;
    if (b >= Bb) return;
    float best = -INFINITY; int bi = 0;
    for (int c = 0; c < Cc; ++c) {
        float v = 2.f * t[b * Cc + c] - q[c];
        if (v > best) { best = v; bi = c; }
    }
    cstar[b] = bi;
}

// dz = (feat>0) ? -2*(h - im[cstar]) : 0, emitted as bf16 hi/lo
__global__ void dz_kernel(const float* __restrict__ feat, const float* __restrict__ h,
                          const float* __restrict__ im, const int* __restrict__ cstar,
                          short* __restrict__ oh, short* __restrict__ ol)
{
    int idx = blockIdx.x * 256 + threadIdx.x;
    if (idx >= Bb * Dd) return;
    int b = idx >> 9, d = idx & 511;
    float f = feat[idx];
    float v = (f > 0.f) ? -2.f * (h[idx] - im[cstar[b] * Dd + d]) : 0.f;
    short hi = f2bf(v);
    oh[idx] = hi; ol[idx] = f2bf(v - bf2f(hi));
}

extern "C" void kernel_launch(void* const* d_in, const int* in_sizes, int n_in,
                              void* d_out, int out_size, void* d_ws, size_t ws_size,
                              hipStream_t stream)
{
    const float* x      = (const float*)d_in[0];  // [1024,3072]
    const float* W      = (const float*)d_in[1];  // [3072,512]
    const float* bias   = (const float*)d_in[2];  // [512]
    const float* mu     = (const float*)d_in[3];  // [100,512]
    const float* invsig = (const float*)d_in[4];  // [512,512] symmetric
    float* out = (float*)d_out;                   // [1024,100]

    char* wp = (char*)d_ws;
    auto alloc = [&](size_t bytes) { char* p = wp; wp += (bytes + 255) & ~size_t(255); return p; };
    short* x_h  = (short*)alloc((size_t)Bb * INn * 2);   // reused as xadv_h
    short* x_l  = (short*)alloc((size_t)Bb * INn * 2);   // reused as xadv_l
    short* Wt_h = (short*)alloc((size_t)Dd * INn * 2);
    short* Wt_l = (short*)alloc((size_t)Dd * INn * 2);
    short* W_h  = (short*)alloc((size_t)INn * Dd * 2);
    short* W_l  = (short*)alloc((size_t)INn * Dd * 2);
    short* is_h = (short*)alloc((size_t)Dd * Dd * 2);
    short* is_l = (short*)alloc((size_t)Dd * Dd * 2);
    short* mu_h = (short*)alloc((size_t)Cc * Dd * 2);
    short* mu_l = (short*)alloc((size_t)Cc * Dd * 2);
    float* part = (float*)alloc((size_t)4 * Bb * Dd * 4);
    float* feat = (float*)alloc((size_t)Bb * Dd * 4);
    short* f_h  = (short*)alloc((size_t)Bb * Dd * 2);
    short* f_l  = (short*)alloc((size_t)Bb * Dd * 2);
    float* h    = (float*)alloc((size_t)Bb * Dd * 4);
    short* h_h  = (short*)alloc((size_t)Bb * Dd * 2);
    short* h_l  = (short*)alloc((size_t)Bb * Dd * 2);
    float* im   = (float*)alloc((size_t)Cc * Dd * 4);
    float* q    = (float*)alloc(512);
    float* s    = (float*)alloc((size_t)Bb * 4);
    int*   cst  = (int*)  alloc((size_t)Bb * 4);
    float* t    = (float*)alloc((size_t)Bb * Cc * 4);
    short* dz_h = (short*)alloc((size_t)Bb * Dd * 2);
    short* dz_l = (short*)alloc((size_t)Bb * Dd * 2);

    dim3 blk(256);

    // Pre-split all fp32 operands to bf16 hi/lo
    split_hl_k<<<(Bb * INn / 4 + 255) / 256, blk, 0, stream>>>(x, x_h, x_l, Bb * INn / 4);
    split_hl_k<<<(INn * Dd / 4 + 255) / 256, blk, 0, stream>>>(W, W_h, W_l, INn * Dd / 4);
    split_hl_k<<<(Dd * Dd / 4 + 255) / 256, blk, 0, stream>>>(invsig, is_h, is_l, Dd * Dd / 4);
    split_hl_k<<<(Cc * Dd / 4 + 255) / 256, blk, 0, stream>>>(mu, mu_h, mu_l, Cc * Dd / 4);
    transpose_split<<<dim3(Dd / 32, INn / 32), blk, 0, stream>>>(W, Wt_h, Wt_l, INn, Dd);

    // im = mu @ invsig ; q[c] = mu_c . im_c
    gemm_hl<0, false><<<dim3(Dd / 64, 1, 1), blk, 0, stream>>>(
        mu_h, mu_l, is_h, is_l, im, Cc, Dd, Dd, Dd, nullptr, nullptr, 0.f, nullptr, nullptr);
    rowdot_kernel<<<Cc, 64, 0, stream>>>(mu, im, q, Dd);

    // Pass A: feat = relu(x@W + b) via split-K=4
    gemm_hl<0, true><<<dim3(Dd / 64, Bb / 128, 4), blk, 0, stream>>>(
        x_h, x_l, Wt_h, Wt_l, part, Bb, Dd, INn, INn / 4, nullptr, nullptr, 0.f, nullptr, nullptr);
    reduce_relu<<<Bb * Dd / 4 / 256, blk, 0, stream>>>(part, bias, feat, f_h, f_l);
    // h = feat @ invsig ; t = h @ mu^T ; argmax
    gemm_hl<4, false><<<dim3(Dd / 64, Bb / 128, 1), blk, 0, stream>>>(
        f_h, f_l, is_h, is_l, h, Bb, Dd, Dd, Dd, nullptr, nullptr, 0.f, h_h, h_l);
    gemm_hl<0, false><<<dim3(2, Bb / 128, 1), blk, 0, stream>>>(
        h_h, h_l, mu_h, mu_l, t, Bb, Cc, Dd, Dd, nullptr, nullptr, 0.f, nullptr, nullptr);
    argmax_kernel<<<Bb / 256, blk, 0, stream>>>(t, q, cst);

    // Backward: dz ; xadv = clip(x + eps * dz@W^T) (hi/lo into x_h/x_l)
    dz_kernel<<<Bb * Dd / 256, blk, 0, stream>>>(feat, h, im, cst, dz_h, dz_l);
    gemm_hl<2, false><<<dim3(INn / 64, Bb / 128, 1), blk, 0, stream>>>(
        dz_h, dz_l, W_h, W_l, nullptr, Bb, INn, Dd, Dd, x, nullptr, EPS_ODIN, x_h, x_l);

    // Pass B
    gemm_hl<0, true><<<dim3(Dd / 64, Bb / 128, 4), blk, 0, stream>>>(
        x_h, x_l, Wt_h, Wt_l, part, Bb, Dd, INn, INn / 4, nullptr, nullptr, 0.f, nullptr, nullptr);
    reduce_relu<<<Bb * Dd / 4 / 256, blk, 0, stream>>>(part, bias, feat, f_h, f_l);
    gemm_hl<4, false><<<dim3(Dd / 64, Bb / 128, 1), blk, 0, stream>>>(
        f_h, f_l, is_h, is_l, h, Bb, Dd, Dd, Dd, nullptr, nullptr, 0.f, h_h, h_l);
    rowdot_kernel<<<Bb, 64, 0, stream>>>(feat, h, s, Dd);
    gemm_hl<3, false><<<dim3(2, Bb / 128, 1), blk, 0, stream>>>(
        h_h, h_l, mu_h, mu_l, out, Bb, Cc, Dd, Dd, s, q, 0.f, nullptr, nullptr);
}